// Round 7
// baseline (214.882 us; speedup 1.0000x reference)
//
#include <hip/hip_runtime.h>
#include <hip/hip_bf16.h>

#define NH 96          // heads
#define NE 1537        // edge table rows
#define ND 5           // multi-hop
#define NN 128         // nodes
#define NB 16          // batch
#define NP1 129        // N+1
#define OUT_PLANE (NP1 * NP1)   // 16641

typedef float f4 __attribute__((ext_vector_type(4), aligned(4)));
typedef float f2 __attribute__((ext_vector_type(2)));

__device__ __forceinline__ float bflo(unsigned u) { return __uint_as_float(u << 16); }
__device__ __forceinline__ float bfhi(unsigned u) { return __uint_as_float(u & 0xffff0000u); }

// ---------------------------------------------------------------------------
// Kernel 1: M2[(d*NE+e)*2+half][64 shorts] (48 head values bf16 + 16 pad):
// 128B-aligned rows so one half-row = exactly one cache line.
// M[d][e][h] = sum_k edge_enc_w[e][k] * W[d][k][h], W[d][k][h]=edge_dis_w[(d*32+k)*96+h]
// ---------------------------------------------------------------------------
__global__ __launch_bounds__(256) void k_build_M(
    const float* __restrict__ E, const float* __restrict__ Wd,
    unsigned short* __restrict__ M) {
  int o = blockIdx.x * 256 + threadIdx.x;          // (d,e,h4): h4 = 4-head group
  if (o >= ND * NE * 24) return;
  int h4 = o % 24;
  int r  = o / 24;                                 // d*NE+e
  int e  = r % NE;
  int d  = r / NE;
  const float* __restrict__ Er = E + e * 32;
  const float4* __restrict__ Wp = (const float4*)(Wd + d * 32 * NH + h4 * 4);
  float4 acc = {0.f, 0.f, 0.f, 0.f};
#pragma unroll 8
  for (int k = 0; k < 32; ++k) {
    float ev = Er[k];
    float4 w = Wp[k * 24];
    acc.x = fmaf(ev, w.x, acc.x);
    acc.y = fmaf(ev, w.y, acc.y);
    acc.z = fmaf(ev, w.z, acc.z);
    acc.w = fmaf(ev, w.w, acc.w);
  }
  const float av[4] = {acc.x, acc.y, acc.z, acc.w};
  unsigned rb[4];
#pragma unroll
  for (int c = 0; c < 4; ++c) {
    unsigned u = __float_as_uint(av[c]);
    rb[c] = (u + 0x7fffu + ((u >> 16) & 1u)) >> 16;   // RTNE to bf16
  }
  const int half = (h4 >= 12);
  unsigned short* mp = M + (size_t)(r * 2 + half) * 64 + (h4 - half * 12) * 4;
  uint2 pk;
  pk.x = rb[0] | (rb[1] << 16);
  pk.y = rb[2] | (rb[3] << 16);
  *(uint2*)mp = pk;   // 8B-aligned
}

// ---------------------------------------------------------------------------
// Kernel 2: interior cells (i>=1, j>=1), split by head-half.
// Block = (b, i, jt 32-wide j tile, head-half of 48). 256 threads = 32 pairs
// x 8 lanes; lanes q=0..5 fetch the pair's 96B half-row with ONE dwordx4.
// R7: pre-scaled byte offsets staged in LDS (kills 6x-redundant addr calc);
// all 15 gathers in flight; float2 accumulate (v_pk_add_f32); float4 stores.
// LDS pad keeps residency at 4 blocks/CU (proven clean-traffic regime).
// ---------------------------------------------------------------------------
__global__ __launch_bounds__(256, 4) void k_interior(
    const float* __restrict__ ab, const int* __restrict__ spos,
    const int* __restrict__ eidx, const float* __restrict__ spw,
    const unsigned short* __restrict__ M, float* __restrict__ out) {
  const int half = blockIdx.x & 1;     // head half: h in [half*48, half*48+48)
  const int jt   = blockIdx.x >> 1;    // 0..3
  const int n  = blockIdx.y;           // 0..127  (i-1)
  const int b  = blockIdx.z;           // 0..15
  const int i  = n + 1;
  const int j0 = jt * 32;

  __shared__ int   s_idx[480];       // 32 pairs x 15 PRE-SCALED byte offsets
  __shared__ int   s_sp[32];
  __shared__ float s_eb[32][49];     // stride-49 (odd): conflict-light
  __shared__ float s_pad[7000];      // occupancy limiter: total LDS ~= 36.3 KB

  const int tid = threadIdx.x;
  if (tid == 0) { volatile float* vp = s_pad; vp[0] = 0.f; }  // keep s_pad

  const int pairbase = (b * NN + n) * NN + j0;   // multiple of 32
  if (tid < 120) {
    int4 raw = ((const int4*)(eidx + (size_t)pairbase * 15))[tid];
    const int ev[4] = {raw.x, raw.y, raw.z, raw.w};
    const int kk = tid * 4;
    int4 sc;
    int* scp = (int*)&sc;
#pragma unroll
    for (int c = 0; c < 4; ++c) {
      const int g = (kk + c) % 15;
      const int d = g / 3;
      scp[c] = ((d * NE + ev[c]) * 2 + half) * 128;   // byte offset of line
    }
    ((int4*)s_idx)[tid] = sc;
  }
  if (tid >= 128 && tid < 160) s_sp[tid - 128] = spos[pairbase + (tid - 128)];
  __syncthreads();

  const int p = tid >> 3;     // pair within tile (0..31)
  const int q = tid & 7;      // lane within pair; q<6 active in gather

  if (q < 6) {
    const char* __restrict__ Mb = (const char*)M;
    const unsigned qoff = q * 16;

    unsigned off[15];
#pragma unroll
    for (int g = 0; g < 15; ++g) off[g] = (unsigned)s_idx[p * 15 + g] + qoff;

    uint4 w[15];
#pragma unroll
    for (int g = 0; g < 15; ++g) w[g] = *(const uint4*)(Mb + off[g]);

    f2 acc2[4];
#pragma unroll
    for (int c = 0; c < 4; ++c) acc2[c] = f2{0.f, 0.f};
#pragma unroll
    for (int g = 0; g < 15; ++g) {
      const unsigned dw[4] = {w[g].x, w[g].y, w[g].z, w[g].w};
#pragma unroll
      for (int c = 0; c < 4; ++c) {
        f2 v;
        v.x = bflo(dw[c]);
        v.y = bfhi(dw[c]);
        acc2[c] += v;            // backend: v_pk_add_f32
      }
    }

    // hop normalizer + spatial bias (16B-aligned float4 chunks)
    const int spn = s_sp[p];
    const int spc = min(max(spn - 1, 1), 5);
    const float scale = 1.0f / (3.0f * (float)spc);
    const f4* __restrict__ sr = (const f4*)(spw + spn * NH + half * 48 + q * 8);
    f4 s0 = sr[0], s1 = sr[1];
    float* eb = &s_eb[p][q * 8];
    eb[0] = acc2[0].x * scale + s0.x;
    eb[1] = acc2[0].y * scale + s0.y;
    eb[2] = acc2[1].x * scale + s0.z;
    eb[3] = acc2[1].y * scale + s0.w;
    eb[4] = acc2[2].x * scale + s1.x;
    eb[5] = acc2[2].y * scale + s1.y;
    eb[6] = acc2[3].x * scale + s1.z;
    eb[7] = acc2[3].y * scale + s1.w;
  }
  __syncthreads();

  // phase B: 192 threads = 48 h x 4 quad-slots; float4 stores (4B-aligned OK)
  if (tid < 192) {
    const int h = tid >> 2;            // 0..47
    const int a = tid & 3;             // 0..3
    const int hh = half * 48 + h;
    float* __restrict__ op =
        out + (size_t)((hh >> 3) * 128 + b * 8 + (hh & 7)) * OUT_PLANE
            + i * NP1 + 1 + j0;
    const float* __restrict__ ar = ab + (b * NP1 + i) * NP1 + 1 + j0;
#pragma unroll
    for (int s = 0; s < 2; ++s) {
      const int jo = a * 4 + s * 16;
      f4 av = *(const f4*)(ar + jo);
      f4 v;
      v.x = fmaf(2.f, av.x, s_eb[jo + 0][h]);
      v.y = fmaf(2.f, av.y, s_eb[jo + 1][h]);
      v.z = fmaf(2.f, av.z, s_eb[jo + 2][h]);
      v.w = fmaf(2.f, av.w, s_eb[jo + 3][h]);
      *(f4*)(op + jo) = v;
    }
  }
}

// ---------------------------------------------------------------------------
// Kernel 3: boundary cells: row i=0 (all j) and column j=0 (i>=1):
//   out = 2*attn_bias + virt_w[h]
// ---------------------------------------------------------------------------
__global__ __launch_bounds__(256) void k_boundary(
    const float* __restrict__ ab, const float* __restrict__ virt,
    float* __restrict__ out) {
  const int bh = blockIdx.x;   // 0..1535 = b*96+h
  const int b = bh / NH;
  const int h = bh % NH;
  const float t = virt[h];
  const int tid = threadIdx.x;
  const size_t base = (size_t)((h >> 3) * 128 + b * 8 + (h & 7)) * OUT_PLANE;
  if (tid < NP1) {
    out[base + tid] = 2.f * ab[(b * NP1) * NP1 + tid] + t;
  }
  if (tid < NN) {
    const int i = tid + 1;     // 1..128
    out[base + i * NP1] = 2.f * ab[(b * NP1 + i) * NP1] + t;
  }
}

// ---------------------------------------------------------------------------
extern "C" void kernel_launch(void* const* d_in, const int* in_sizes, int n_in,
                              void* d_out, int out_size, void* d_ws, size_t ws_size,
                              hipStream_t stream) {
  const float* ab   = (const float*)d_in[0];   // attn_bias     [16,129,129] f32
  const int*   spos = (const int*)d_in[1];     // spatial_pos   [16,128,128] i32
  // d_in[2] node_attr: unused by reference math
  const int*   eidx = (const int*)d_in[3];     // edge_input    [16,128,128,5,3] i32
  const float* eenc = (const float*)d_in[4];   // edge_enc_w    [1537,32] f32
  const float* edis = (const float*)d_in[5];   // edge_dis_w    [393216,1] f32
  const float* spw  = (const float*)d_in[6];   // spatial_enc_w [522,96] f32
  const float* virt = (const float*)d_in[7];   // virt_w        [1,96] f32
  float* out = (float*)d_out;

  unsigned short* M = (unsigned short*)d_ws;   // 5*1537*2 rows x 128B = 1.97 MB

  const int totM = ND * NE * 24;
  k_build_M<<<(totM + 255) / 256, 256, 0, stream>>>(eenc, edis, M);
  k_interior<<<dim3(8, NN, NB), 256, 0, stream>>>(ab, spos, eidx, spw, M, out);
  k_boundary<<<NB * NH, 256, 0, stream>>>(ab, virt, out);
}